// Round 2
// baseline (531.545 us; speedup 1.0000x reference)
//
#include <hip/hip_runtime.h>

// Problem constants (match reference shapes)
#define B_ 2
#define N_ 8192
#define T_ 32
#define C_ 64
#define K_ 16
#define NB_ 4

#define NC 16   // nodes per block
#define TC 2    // t-rows per phase (per batch)
// grid: x = N/NC = 512 node-chunks, y = B * T/TC = 32 phases
// Phase y covers (b = y>>4, t in {2*(y&15), 2*(y&15)+1}).
// Dispatch is x-fastest => phases run roughly in order, keeping the 4 MiB
// per-phase z slice L2/L3-resident for the random-neighbor gather.

typedef float f4v __attribute__((ext_vector_type(4)));

__global__ __launch_bounds__(256) void geodcd_kernel(
    const float* __restrict__ z,      // (B, N, T, C)
    const int*   __restrict__ nidx,   // (N, K)
    const float* __restrict__ adj,    // (N, K)
    const float* __restrict__ bw,     // (NB, N, K)
    const float* __restrict__ cc,     // (C, NB)
    float*       __restrict__ out)    // (B, N, T, C)
{
    const int tid = threadIdx.x;
    const int n0  = blockIdx.x * NC;
    const int ph  = blockIdx.y;            // 0..31
    const int b   = ph >> 4;               // batch
    const int t0  = (ph & 15) * TC;        // first t-row of this phase

    __shared__ __align__(16) float qs[NC][K_][NB_];  // adj * bw, 4 KiB
    __shared__ int idx_s[NC][K_];                    // 1 KiB

    // Stage neighbor indices (256 elems, 1 per thread)
    {
        const int nl = tid >> 4, k = tid & 15;
        idx_s[nl][k] = nidx[(n0 + nl) * K_ + k];
    }
    // Stage q[nl][k][b] = adj[n,k] * bw[b,n,k]  (1024 elems, 4 per thread)
    for (int i = tid; i < NC * K_ * NB_; i += 256) {
        const int nl = i >> 6;
        const int k  = (i >> 2) & 15;
        const int bb = i & 3;
        qs[nl][k][bb] = adj[(n0 + nl) * K_ + k] * bw[(bb * N_ + (n0 + nl)) * K_ + k];
    }
    __syncthreads();

    const int lane = tid & 15;    // covers C=64 via float4
    const int nl   = tid >> 4;    // local node 0..15
    const int c4   = lane * 4;
    const int n    = n0 + nl;

    // cc fragment: ccv[j][b] = cc[c4+j][b]
    f4v ccv[4];
#pragma unroll
    for (int j = 0; j < 4; ++j)
        ccv[j] = *(const f4v*)&cc[(c4 + j) * NB_];

    // Build this thread's edge weights: w[k][j] = sum_b ccv[j][b] * q[nl][k][b]
    f4v w[K_];
#pragma unroll
    for (int k = 0; k < K_; ++k) {
        const f4v q = *(const f4v*)qs[nl][k];
        f4v wv;
        wv.x = ccv[0].x * q.x + ccv[0].y * q.y + ccv[0].z * q.z + ccv[0].w * q.w;
        wv.y = ccv[1].x * q.x + ccv[1].y * q.y + ccv[1].z * q.z + ccv[1].w * q.w;
        wv.z = ccv[2].x * q.x + ccv[2].y * q.y + ccv[2].z * q.z + ccv[2].w * q.w;
        wv.w = ccv[3].x * q.x + ccv[3].y * q.y + ccv[3].z * q.z + ccv[3].w * q.w;
        w[k] = wv;
    }

    // Gather offsets for row t0 (row t0+1 is +C_ elements)
    int off[K_];
#pragma unroll
    for (int k = 0; k < K_; ++k)
        off[k] = idx_s[nl][k] * (T_ * C_) + t0 * C_ + c4;

    const float* zb = z + (size_t)b * (N_ * T_ * C_);
    f4v a0 = {0.f, 0.f, 0.f, 0.f};
    f4v a1 = {0.f, 0.f, 0.f, 0.f};
#pragma unroll
    for (int k = 0; k < K_; ++k) {
        const float* p = zb + off[k];
        const f4v v0 = *(const f4v*)p;
        const f4v v1 = *(const f4v*)(p + C_);
        a0.x += v0.x * w[k].x;  a0.y += v0.y * w[k].y;
        a0.z += v0.z * w[k].z;  a0.w += v0.w * w[k].w;
        a1.x += v1.x * w[k].x;  a1.y += v1.y * w[k].y;
        a1.z += v1.z * w[k].z;  a1.w += v1.w * w[k].w;
    }

    // tanh(x) = 1 - 2/(exp(2x)+1)
    f4v r0, r1;
    r0.x = 1.f - 2.f / (__expf(2.f * a0.x) + 1.f);
    r0.y = 1.f - 2.f / (__expf(2.f * a0.y) + 1.f);
    r0.z = 1.f - 2.f / (__expf(2.f * a0.z) + 1.f);
    r0.w = 1.f - 2.f / (__expf(2.f * a0.w) + 1.f);
    r1.x = 1.f - 2.f / (__expf(2.f * a1.x) + 1.f);
    r1.y = 1.f - 2.f / (__expf(2.f * a1.y) + 1.f);
    r1.z = 1.f - 2.f / (__expf(2.f * a1.z) + 1.f);
    r1.w = 1.f - 2.f / (__expf(2.f * a1.w) + 1.f);

    // Nontemporal: don't let the 128 MiB output stream evict the hot z slice
    float* ob = out + (((size_t)b * N_ + n) * T_ + t0) * C_ + c4;
    __builtin_nontemporal_store(r0, (f4v*)ob);
    __builtin_nontemporal_store(r1, (f4v*)(ob + C_));
}

extern "C" void kernel_launch(void* const* d_in, const int* in_sizes, int n_in,
                              void* d_out, int out_size, void* d_ws, size_t ws_size,
                              hipStream_t stream) {
    const float* z    = (const float*)d_in[0];
    const int*   nidx = (const int*)  d_in[1];
    const float* adj  = (const float*)d_in[2];
    const float* bw   = (const float*)d_in[3];
    const float* cc   = (const float*)d_in[4];
    float*       out  = (float*)d_out;

    dim3 grid(N_ / NC, B_ * (T_ / TC));
    geodcd_kernel<<<grid, 256, 0, stream>>>(z, nidx, adj, bw, cc, out);
}